// Round 3
// baseline (836.062 us; speedup 1.0000x reference)
//
#include <hip/hip_runtime.h>

#define N_NODES 100000
#define N_EDGES 1600000

typedef short s8v __attribute__((ext_vector_type(8)));
typedef float f4v __attribute__((ext_vector_type(4)));
typedef unsigned short us4 __attribute__((ext_vector_type(4)));

__device__ inline unsigned short f2bf(float f) {
    unsigned int u = __float_as_uint(f);
    u += 0x7FFFu + ((u >> 16) & 1u);   // round-to-nearest-even
    return (unsigned short)(u >> 16);
}

__device__ inline float silu_f(float v) {
    return v / (1.0f + __expf(-v));
}

// ---------------------------------------------------------------------------
// Prepass: x (f32, [N,64]) -> bf16 copy in workspace.
// ---------------------------------------------------------------------------
__global__ __launch_bounds__(256) void x2bf_kernel(const float* __restrict__ x,
                                                   unsigned short* __restrict__ xb)
{
    const int total = N_NODES * 64 / 4;
    for (int i = blockIdx.x * blockDim.x + threadIdx.x; i < total;
         i += gridDim.x * blockDim.x) {
        f4v v = *(const f4v*)(x + (size_t)i * 4);
        us4 o;
        #pragma unroll
        for (int q = 0; q < 4; ++q) o[q] = f2bf(v[q]);
        *(us4*)(xb + (size_t)i * 4) = o;
    }
}

// ---------------------------------------------------------------------------
// CSR build: histogram -> 2-level scan -> permutation
// ---------------------------------------------------------------------------
__global__ __launch_bounds__(256) void hist_kernel(const int* __restrict__ eidx,
                                                   int* cnt)
{
    for (int e = blockIdx.x * blockDim.x + threadIdx.x; e < N_EDGES;
         e += gridDim.x * blockDim.x)
        atomicAdd(&cnt[eidx[e]], 1);
}

#define SCAN_NBLK 98   // 98*1024 >= 100000

__global__ __launch_bounds__(1024) void scanA_kernel(const int* __restrict__ cnt,
                                                     int* base, int* bsum)
{
    __shared__ int sh[1024];
    const int t = threadIdx.x;
    const int i = blockIdx.x * 1024 + t;
    int c = (i < N_NODES) ? cnt[i] : 0;
    sh[t] = c;
    __syncthreads();
    for (int off = 1; off < 1024; off <<= 1) {
        int v = (t >= off) ? sh[t - off] : 0;
        __syncthreads();
        sh[t] += v;
        __syncthreads();
    }
    if (i < N_NODES) base[i] = sh[t];          // inclusive for now
    if (t == 1023) bsum[blockIdx.x] = sh[1023];
}

__global__ __launch_bounds__(128) void scanB_kernel(const int* __restrict__ bsum,
                                                    int* boff)
{
    __shared__ int sh[128];
    const int t = threadIdx.x;
    int v = (t < SCAN_NBLK) ? bsum[t] : 0;
    sh[t] = v;
    __syncthreads();
    for (int off = 1; off < 128; off <<= 1) {
        int u = (t >= off) ? sh[t - off] : 0;
        __syncthreads();
        sh[t] += u;
        __syncthreads();
    }
    boff[t] = sh[t] - v;   // exclusive
}

__global__ __launch_bounds__(256) void scanC_kernel(const int* __restrict__ cnt,
                                                    int* base, const int* __restrict__ boff,
                                                    int* cur)
{
    const int i = blockIdx.x * 256 + threadIdx.x;
    if (i < N_NODES) {
        int b = base[i] - cnt[i] + boff[i >> 10];   // exclusive prefix
        base[i] = b;
        cur[i]  = b;
    }
}

// elist entry: .x = e | (row&63)<<25  (e < 2^21), .y = col
__global__ __launch_bounds__(256) void perm_kernel(const int* __restrict__ eidx,
                                                   int* cur, int2* __restrict__ elist)
{
    for (int e = blockIdx.x * blockDim.x + threadIdx.x; e < N_EDGES;
         e += gridDim.x * blockDim.x) {
        int r = eidx[e];
        int c = eidx[N_EDGES + e];
        int pos = atomicAdd(&cur[r], 1);
        elist[pos] = make_int2(e | ((r & 63) << 25), c);
    }
}

// ---------------------------------------------------------------------------
// Fused kernel: block = 64 nodes + all their edges (sorted slice).
//   edge phase : 16-edge MFMA tiles -> m_ij -> ds_add_f32 into AGG (LDS)
//   node phase : [x | AGG] @ Wn1 -> silu -> @ Wn2 -> out
// LDS: W1L 20480 + W2L 8192 + HL 16384 + AGG 16640 = 61696 B -> 2 blocks/CU.
// ---------------------------------------------------------------------------
__global__ __launch_bounds__(512, 4) void fused_kernel(
    const unsigned short* __restrict__ xb, const float* __restrict__ ef,
    const int* __restrict__ base, const int2* __restrict__ elist,
    const float* __restrict__ We1, const float* __restrict__ be1,
    const float* __restrict__ We2, const float* __restrict__ be2,
    const float* __restrict__ Wn1, const float* __restrict__ bn1,
    const float* __restrict__ Wn2, const float* __restrict__ bn2,
    float* __restrict__ out)
{
    __shared__ unsigned short W1L[64 * 160];     // edge We1, later node Wn1 (16KB of it)
    __shared__ unsigned short W2L[64 * 64];      // edge We2, later node Wn2
    __shared__ unsigned short HL[8][2][64][8];   // per-wave H staging
    __shared__ float AGG[65][64];                // row 64 = trash row for tail lanes

    const int tid = threadIdx.x;

    // --- stage edge weights (fragment-major bf16) + zero AGG ---
    for (int i = tid; i < 64 * 160; i += 512) {
        int row = i / 160, k = i - row * 160;
        int t = row >> 4, lr = row & 15, s = k >> 5, kg = (k >> 3) & 3, j = k & 7;
        W1L[(((t * 5 + s) * 64) + (kg * 16 + lr)) * 8 + j] = f2bf(We1[i]);
    }
    for (int i = tid; i < 64 * 64; i += 512) {
        int row = i >> 6, k = i & 63;
        int t = row >> 4, lr = row & 15, s = k >> 5, kg = (k >> 3) & 3, j = k & 7;
        W2L[(((t * 2 + s) * 64) + (kg * 16 + lr)) * 8 + j] = f2bf(We2[i]);
    }
    for (int i = tid; i < 65 * 64; i += 512) ((float*)AGG)[i] = 0.0f;
    __syncthreads();

    const int lane = tid & 63;
    const int wv   = tid >> 6;      // 0..7
    const int lrow = lane & 15;
    const int lkg  = lane >> 4;

    const int n0    = blockIdx.x * 64;
    const int base0 = base[n0];
    const int end   = (n0 + 64 <= N_NODES) ? base[n0 + 64] : N_EDGES;

    float b1f[4], b2f[4];
    #pragma unroll
    for (int t = 0; t < 4; ++t) {
        b1f[t] = be1[t * 16 + lrow];
        b2f[t] = be2[t * 16 + lrow];
    }

    // ---------------- edge phase (no barriers, waves independent) ----------
    for (int t0 = base0 + wv * 16; t0 < end; t0 += 8 * 16) {
        const int  idx   = t0 + lrow;
        const bool valid = idx < end;
        int2 ent = elist[valid ? idx : base0];
        const int e     = ent.x & 0x1FFFFFF;
        const int ar    = valid ? (ent.x >> 25) : 64;     // 64 = trash row
        const int c     = ent.y;
        const int rowid = n0 + (ent.x >> 25);             // real node, L1-hot

        s8v afr[5];
        afr[0] = *(const s8v*)(xb + (size_t)rowid * 64 + lkg * 8);
        afr[1] = *(const s8v*)(xb + (size_t)rowid * 64 + 32 + lkg * 8);
        afr[2] = *(const s8v*)(xb + (size_t)c * 64 + lkg * 8);
        afr[3] = *(const s8v*)(xb + (size_t)c * 64 + 32 + lkg * 8);
        {
            const float* ep = ef + (size_t)e * 32 + lkg * 8;
            f4v elo = *(const f4v*)ep;
            f4v ehi = *(const f4v*)(ep + 4);
            s8v a4;
            #pragma unroll
            for (int q = 0; q < 4; ++q) {
                a4[q]     = (short)f2bf(elo[q]);
                a4[q + 4] = (short)f2bf(ehi[q]);
            }
            afr[4] = a4;
        }

        // GEMM1 [16,160] x [160,64]
        f4v acc[4] = {f4v(0), f4v(0), f4v(0), f4v(0)};
        #pragma unroll
        for (int s = 0; s < 5; ++s) {
            #pragma unroll
            for (int t = 0; t < 4; ++t) {
                s8v b = *(const s8v*)&W1L[((t * 5 + s) * 64 + lane) * 8];
                acc[t] = __builtin_amdgcn_mfma_f32_16x16x32_bf16(afr[s], b, acc[t], 0, 0, 0);
            }
        }

        // silu -> HL (wave-private, fragment-major)
        #pragma unroll
        for (int t = 0; t < 4; ++t) {
            const int col = t * 16 + lrow;
            const int s = col >> 5, lsub = (col & 31) >> 3, j = col & 7;
            #pragma unroll
            for (int rr = 0; rr < 4; ++rr) {
                float v = silu_f(acc[t][rr] + b1f[t]);
                HL[wv][s][lsub * 16 + (lkg * 4 + rr)][j] = f2bf(v);
            }
        }

        // GEMM2 [16,64] x [64,64]
        s8v h0 = *(const s8v*)&HL[wv][0][lane][0];
        s8v h1 = *(const s8v*)&HL[wv][1][lane][0];
        f4v c2[4] = {f4v(0), f4v(0), f4v(0), f4v(0)};
        #pragma unroll
        for (int t = 0; t < 4; ++t) {
            s8v b0 = *(const s8v*)&W2L[((t * 2 + 0) * 64 + lane) * 8];
            s8v b1 = *(const s8v*)&W2L[((t * 2 + 1) * 64 + lane) * 8];
            c2[t] = __builtin_amdgcn_mfma_f32_16x16x32_bf16(h0, b0, c2[t], 0, 0, 0);
            c2[t] = __builtin_amdgcn_mfma_f32_16x16x32_bf16(h1, b1, c2[t], 0, 0, 0);
        }

        // silu -> LDS segment-sum
        #pragma unroll
        for (int rr = 0; rr < 4; ++rr) {
            const int arb = __shfl(ar, lkg * 4 + rr);
            #pragma unroll
            for (int t = 0; t < 4; ++t) {
                float v = silu_f(c2[t][rr] + b2f[t]);
                atomicAdd(&AGG[arb][t * 16 + lrow], v);
            }
        }
    }
    __syncthreads();

    // --- restage node weights into same LDS ---
    for (int i = tid; i < 64 * 128; i += 512) {
        int row = i >> 7, k = i & 127;
        int t = row >> 4, lr = row & 15, s = k >> 5, kg = (k >> 3) & 3, j = k & 7;
        W1L[(((t * 4 + s) * 64) + (kg * 16 + lr)) * 8 + j] = f2bf(Wn1[i]);
    }
    for (int i = tid; i < 64 * 64; i += 512) {
        int row = i >> 6, k = i & 63;
        int t = row >> 4, lr = row & 15, s = k >> 5, kg = (k >> 3) & 3, j = k & 7;
        W2L[(((t * 2 + s) * 64) + (kg * 16 + lr)) * 8 + j] = f2bf(Wn2[i]);
    }
    __syncthreads();

    // ---------------- node phase (waves 0..3, 16 rows each) ----------------
    if (wv < 4) {
        const int m0 = wv * 16;
        float n1f[4], n2f[4];
        #pragma unroll
        for (int t = 0; t < 4; ++t) {
            n1f[t] = bn1[t * 16 + lrow];
            n2f[t] = bn2[t * 16 + lrow];
        }

        const int n  = n0 + m0 + lrow;
        const int nc = (n < N_NODES) ? n : (N_NODES - 1);

        s8v a[4];
        a[0] = *(const s8v*)(xb + (size_t)nc * 64 + lkg * 8);
        a[1] = *(const s8v*)(xb + (size_t)nc * 64 + 32 + lkg * 8);
        #pragma unroll
        for (int s = 0; s < 2; ++s) {
            f4v g0 = *(const f4v*)&AGG[m0 + lrow][s * 32 + lkg * 8];
            f4v g1 = *(const f4v*)&AGG[m0 + lrow][s * 32 + lkg * 8 + 4];
            s8v av;
            #pragma unroll
            for (int q = 0; q < 4; ++q) {
                av[q]     = (short)f2bf(g0[q]);
                av[q + 4] = (short)f2bf(g1[q]);
            }
            a[2 + s] = av;
        }

        f4v acc[4] = {f4v(0), f4v(0), f4v(0), f4v(0)};
        #pragma unroll
        for (int s = 0; s < 4; ++s) {
            #pragma unroll
            for (int t = 0; t < 4; ++t) {
                s8v b = *(const s8v*)&W1L[((t * 4 + s) * 64 + lane) * 8];
                acc[t] = __builtin_amdgcn_mfma_f32_16x16x32_bf16(a[s], b, acc[t], 0, 0, 0);
            }
        }

        #pragma unroll
        for (int t = 0; t < 4; ++t) {
            const int col = t * 16 + lrow;
            const int s = col >> 5, lsub = (col & 31) >> 3, j = col & 7;
            #pragma unroll
            for (int rr = 0; rr < 4; ++rr) {
                float v = silu_f(acc[t][rr] + n1f[t]);
                HL[wv][s][lsub * 16 + (lkg * 4 + rr)][j] = f2bf(v);
            }
        }

        s8v h0 = *(const s8v*)&HL[wv][0][lane][0];
        s8v h1 = *(const s8v*)&HL[wv][1][lane][0];
        f4v c2[4] = {f4v(0), f4v(0), f4v(0), f4v(0)};
        #pragma unroll
        for (int t = 0; t < 4; ++t) {
            s8v b0 = *(const s8v*)&W2L[((t * 2 + 0) * 64 + lane) * 8];
            s8v b1 = *(const s8v*)&W2L[((t * 2 + 1) * 64 + lane) * 8];
            c2[t] = __builtin_amdgcn_mfma_f32_16x16x32_bf16(h0, b0, c2[t], 0, 0, 0);
            c2[t] = __builtin_amdgcn_mfma_f32_16x16x32_bf16(h1, b1, c2[t], 0, 0, 0);
        }

        #pragma unroll
        for (int rr = 0; rr < 4; ++rr) {
            const int nrow = n0 + m0 + lkg * 4 + rr;
            if (nrow < N_NODES) {
                float* dst = out + (size_t)nrow * 64;
                #pragma unroll
                for (int t = 0; t < 4; ++t)
                    dst[t * 16 + lrow] = c2[t][rr] + n2f[t];
            }
        }
    }
}

// ---------------------------------------------------------------------------
// Fallback (round-2 path) if ws is too small for CSR buffers.
// ---------------------------------------------------------------------------
__global__ __launch_bounds__(256, 4) void edge_kernel_fb(
    const unsigned short* __restrict__ xb, const int* __restrict__ eidx,
    const float* __restrict__ ef,
    const float* __restrict__ We1, const float* __restrict__ be1,
    const float* __restrict__ We2, const float* __restrict__ be2,
    float* agg)
{
    __shared__ unsigned short W1L[64 * 160];
    __shared__ unsigned short W2L[64 * 64];
    __shared__ unsigned short HL[4][2][64][8];

    const int tid = threadIdx.x;
    for (int i = tid; i < 64 * 160; i += 256) {
        int row = i / 160, k = i - row * 160;
        int t = row >> 4, lr = row & 15, s = k >> 5, kg = (k >> 3) & 3, j = k & 7;
        W1L[(((t * 5 + s) * 64) + (kg * 16 + lr)) * 8 + j] = f2bf(We1[i]);
    }
    for (int i = tid; i < 64 * 64; i += 256) {
        int row = i >> 6, k = i & 63;
        int t = row >> 4, lr = row & 15, s = k >> 5, kg = (k >> 3) & 3, j = k & 7;
        W2L[(((t * 2 + s) * 64) + (kg * 16 + lr)) * 8 + j] = f2bf(We2[i]);
    }
    __syncthreads();

    const int lane = tid & 63, wv = tid >> 6, lrow = lane & 15, lkg = lane >> 4;
    float b1f[4], b2f[4];
    #pragma unroll
    for (int t = 0; t < 4; ++t) { b1f[t] = be1[t*16+lrow]; b2f[t] = be2[t*16+lrow]; }

    const int wave_id = blockIdx.x * 4 + wv, n_waves = gridDim.x * 4;
    for (int grp = wave_id; grp < N_EDGES / 16; grp += n_waves) {
        const int e0 = grp * 16;
        const int r = eidx[e0 + lrow];
        const int c = eidx[N_EDGES + e0 + lrow];
        s8v afr[5];
        afr[0] = *(const s8v*)(xb + (size_t)r * 64 + lkg * 8);
        afr[1] = *(const s8v*)(xb + (size_t)r * 64 + 32 + lkg * 8);
        afr[2] = *(const s8v*)(xb + (size_t)c * 64 + lkg * 8);
        afr[3] = *(const s8v*)(xb + (size_t)c * 64 + 32 + lkg * 8);
        {
            const float* ep = ef + (size_t)(e0 + lrow) * 32 + lkg * 8;
            f4v elo = *(const f4v*)ep, ehi = *(const f4v*)(ep + 4);
            s8v a4;
            #pragma unroll
            for (int q = 0; q < 4; ++q) { a4[q] = (short)f2bf(elo[q]); a4[q+4] = (short)f2bf(ehi[q]); }
            afr[4] = a4;
        }
        f4v acc[4] = {f4v(0), f4v(0), f4v(0), f4v(0)};
        #pragma unroll
        for (int s = 0; s < 5; ++s)
            #pragma unroll
            for (int t = 0; t < 4; ++t) {
                s8v b = *(const s8v*)&W1L[((t * 5 + s) * 64 + lane) * 8];
                acc[t] = __builtin_amdgcn_mfma_f32_16x16x32_bf16(afr[s], b, acc[t], 0, 0, 0);
            }
        #pragma unroll
        for (int t = 0; t < 4; ++t) {
            const int col = t*16+lrow, s = col >> 5, lsub = (col & 31) >> 3, j = col & 7;
            #pragma unroll
            for (int rr = 0; rr < 4; ++rr)
                HL[wv][s][lsub*16 + (lkg*4+rr)][j] = f2bf(silu_f(acc[t][rr] + b1f[t]));
        }
        s8v h0 = *(const s8v*)&HL[wv][0][lane][0];
        s8v h1 = *(const s8v*)&HL[wv][1][lane][0];
        f4v c2[4] = {f4v(0), f4v(0), f4v(0), f4v(0)};
        #pragma unroll
        for (int t = 0; t < 4; ++t) {
            s8v b0 = *(const s8v*)&W2L[((t*2+0)*64+lane)*8];
            s8v b1 = *(const s8v*)&W2L[((t*2+1)*64+lane)*8];
            c2[t] = __builtin_amdgcn_mfma_f32_16x16x32_bf16(h0, b0, c2[t], 0, 0, 0);
            c2[t] = __builtin_amdgcn_mfma_f32_16x16x32_bf16(h1, b1, c2[t], 0, 0, 0);
        }
        #pragma unroll
        for (int rr = 0; rr < 4; ++rr) {
            const int node = __shfl(r, lkg * 4 + rr);
            float* dst = agg + (size_t)node * 64;
            #pragma unroll
            for (int t = 0; t < 4; ++t)
                atomicAdd(dst + t * 16 + lrow, silu_f(c2[t][rr] + b2f[t]));
        }
    }
}

__global__ __launch_bounds__(256) void node_kernel_fb(
    const float* __restrict__ x,
    const float* __restrict__ Wn1, const float* __restrict__ bn1,
    const float* __restrict__ Wn2, const float* __restrict__ bn2,
    float* io)
{
    __shared__ unsigned short A[64][136];
    __shared__ unsigned short W1[64][136];
    __shared__ unsigned short H[64][72];
    __shared__ unsigned short W2[64][72];
    __shared__ float B1[64];
    __shared__ float B2[64];

    const int tid = threadIdx.x;
    for (int i = tid; i < 64 * 128; i += 256) W1[i >> 7][i & 127] = f2bf(Wn1[i]);
    for (int i = tid; i < 64 * 64; i += 256) W2[i >> 6][i & 63] = f2bf(Wn2[i]);
    if (tid < 64) { B1[tid] = bn1[tid]; B2[tid] = bn2[tid]; }

    const int n0 = blockIdx.x * 64, g = tid >> 4, l16 = tid & 15;
    #pragma unroll
    for (int i = 0; i < 4; ++i) {
        int e = g + i * 16, n = n0 + e;
        if (n >= N_NODES) n = N_NODES - 1;
        f4v xv = *(const f4v*)(x + (size_t)n * 64 + l16 * 4);
        us4 av;
        #pragma unroll
        for (int q = 0; q < 4; ++q) av[q] = f2bf(xv[q]);
        *(us4*)&A[e][l16 * 4] = av;
        f4v gv = *(const f4v*)(io + (size_t)n * 64 + l16 * 4);
        us4 ag;
        #pragma unroll
        for (int q = 0; q < 4; ++q) ag[q] = f2bf(gv[q]);
        *(us4*)&A[e][64 + l16 * 4] = ag;
    }
    __syncthreads();

    const int lane = tid & 63, m0 = (tid >> 6) * 16, lrow = lane & 15, lkg = lane >> 4;
    f4v a0 = 0, a1 = 0, a2 = 0, a3 = 0;
    #pragma unroll
    for (int s = 0; s < 4; ++s) {
        int k0 = s * 32 + lkg * 8;
        s8v av = *(const s8v*)&A[m0 + lrow][k0];
        a0 = __builtin_amdgcn_mfma_f32_16x16x32_bf16(av, *(const s8v*)&W1[ 0+lrow][k0], a0, 0, 0, 0);
        a1 = __builtin_amdgcn_mfma_f32_16x16x32_bf16(av, *(const s8v*)&W1[16+lrow][k0], a1, 0, 0, 0);
        a2 = __builtin_amdgcn_mfma_f32_16x16x32_bf16(av, *(const s8v*)&W1[32+lrow][k0], a2, 0, 0, 0);
        a3 = __builtin_amdgcn_mfma_f32_16x16x32_bf16(av, *(const s8v*)&W1[48+lrow][k0], a3, 0, 0, 0);
    }
    {
        f4v accs[4] = {a0, a1, a2, a3};
        #pragma unroll
        for (int t = 0; t < 4; ++t) {
            int col = t * 16 + lrow;
            float bias = B1[col];
            #pragma unroll
            for (int r = 0; r < 4; ++r)
                H[m0 + lkg * 4 + r][col] = f2bf(silu_f(accs[t][r] + bias));
        }
    }
    f4v c0 = 0, c1 = 0, c2 = 0, c3 = 0;
    #pragma unroll
    for (int s = 0; s < 2; ++s) {
        int k0 = s * 32 + lkg * 8;
        s8v av = *(const s8v*)&H[m0 + lrow][k0];
        c0 = __builtin_amdgcn_mfma_f32_16x16x32_bf16(av, *(const s8v*)&W2[ 0+lrow][k0], c0, 0, 0, 0);
        c1 = __builtin_amdgcn_mfma_f32_16x16x32_bf16(av, *(const s8v*)&W2[16+lrow][k0], c1, 0, 0, 0);
        c2 = __builtin_amdgcn_mfma_f32_16x16x32_bf16(av, *(const s8v*)&W2[32+lrow][k0], c2, 0, 0, 0);
        c3 = __builtin_amdgcn_mfma_f32_16x16x32_bf16(av, *(const s8v*)&W2[48+lrow][k0], c3, 0, 0, 0);
    }
    {
        f4v cs[4] = {c0, c1, c2, c3};
        #pragma unroll
        for (int r = 0; r < 4; ++r) {
            int n = n0 + m0 + lkg * 4 + r;
            if (n < N_NODES) {
                float* dst = io + (size_t)n * 64;
                #pragma unroll
                for (int t = 0; t < 4; ++t) dst[t * 16 + lrow] = cs[t][r] + B2[t * 16 + lrow];
            }
        }
    }
}

extern "C" void kernel_launch(void* const* d_in, const int* in_sizes, int n_in,
                              void* d_out, int out_size, void* d_ws, size_t ws_size,
                              hipStream_t stream) {
    const float* x    = (const float*)d_in[0];
    const int*   eidx = (const int*)  d_in[1];
    const float* ef   = (const float*)d_in[2];
    const float* We1  = (const float*)d_in[3];
    const float* be1  = (const float*)d_in[4];
    const float* We2  = (const float*)d_in[5];
    const float* be2  = (const float*)d_in[6];
    const float* Wn1  = (const float*)d_in[7];
    const float* bn1  = (const float*)d_in[8];
    const float* Wn2  = (const float*)d_in[9];
    const float* bn2  = (const float*)d_in[10];
    float* out = (float*)d_out;

    char* ws = (char*)d_ws;
    // ws layout
    unsigned short* xb = (unsigned short*)ws;                    // 12,800,000 B
    int*  cnt   = (int*) (ws + 12800000);                        //    400,000
    int*  basep = (int*) (ws + 13200000);                        //    400,000
    int*  cur   = (int*) (ws + 13600000);                        //    400,000
    int*  bsum  = (int*) (ws + 14000000);                        //        512
    int*  boff  = (int*) (ws + 14000512);                        //        512
    int2* elist = (int2*)(ws + 14001024);                        // 12,800,000
    const size_t WS_NEEDED = 26801024;

    x2bf_kernel<<<1024, 256, 0, stream>>>(x, xb);

    if (ws_size >= WS_NEEDED) {
        hipMemsetAsync(cnt, 0, N_NODES * sizeof(int), stream);
        hist_kernel<<<2048, 256, 0, stream>>>(eidx, cnt);
        scanA_kernel<<<SCAN_NBLK, 1024, 0, stream>>>(cnt, basep, bsum);
        scanB_kernel<<<1, 128, 0, stream>>>(bsum, boff);
        scanC_kernel<<<(N_NODES + 255) / 256, 256, 0, stream>>>(cnt, basep, boff, cur);
        perm_kernel<<<2048, 256, 0, stream>>>(eidx, cur, elist);
        fused_kernel<<<(N_NODES + 63) / 64, 512, 0, stream>>>(
            xb, ef, basep, elist, We1, be1, We2, be2, Wn1, bn1, Wn2, bn2, out);
    } else {
        hipMemsetAsync(d_out, 0, (size_t)N_NODES * 64 * sizeof(float), stream);
        edge_kernel_fb<<<1024, 256, 0, stream>>>(xb, eidx, ef, We1, be1, We2, be2, out);
        node_kernel_fb<<<(N_NODES + 63) / 64, 256, 0, stream>>>(x, Wn1, bn1, Wn2, bn2, out);
    }
}